// Round 12
// baseline (868.132 us; speedup 1.0000x reference)
//
#include <hip/hip_runtime.h>
#include <hip/hip_bf16.h>
#include <math.h>

#define N_TOK 8192
#define DMODEL 512
#define NHEAD 8
#define HDIM 64
#define SEQ 512
#define BATCH 16
#define FFDIM 2048
#define NLAYER 6
#define NCLS 10000
#define VD_SC 8          // s-chunks for fin_vd split-K

typedef unsigned short u16;
typedef __attribute__((ext_vector_type(8))) short bf16x8;
typedef __attribute__((ext_vector_type(8))) unsigned short u16x8;
typedef __attribute__((ext_vector_type(4))) unsigned short u16x4;
typedef __attribute__((ext_vector_type(4))) float f32x4;

__device__ __forceinline__ u16 f2b(float x) {   // RNE f32 -> bf16 (finite inputs)
    unsigned int u = __float_as_uint(x);
    u += 0x7fffu + ((u >> 16) & 1u);
    return (u16)(u >> 16);
}

__device__ __forceinline__ void gl_lds16(const void* g, void* l) {
    __builtin_amdgcn_global_load_lds(
        (const __attribute__((address_space(1))) unsigned int*)g,
        (__attribute__((address_space(3))) unsigned int*)l, 16, 0, 0);
}

// ---------------- positional table: fp64 rotation recurrence ------------------
__global__ __launch_bounds__(512) void pos_kernel(float* __restrict__ pos) {
    const int i = threadIdx.x;
    const int s0 = blockIdx.x * 32;
    const double bse = pow(10000.0, -(double)(i & ~1) / 512.0);
    const double cb = cos(bse), sb = sin(bse);
    const double a0 = (double)s0 * bse;
    double sn = sin(a0), cs = cos(a0);
    const bool odd = i & 1;
    for (int k = 0; k < 32; ++k) {
        pos[(size_t)(s0 + k) * 512 + i] = (float)(odd ? cs : sn);
        const double ns = sn * cb + cs * sb;
        cs = cs * cb - sn * sb;
        sn = ns;
    }
}

// ---------------- embedding: C = 2*emb[x] + pos (f32 + bf16 copies) ----------
__global__ __launch_bounds__(256) void embed_kernel(const int* __restrict__ xi,
        const float* __restrict__ emb, const float* __restrict__ pos,
        float* __restrict__ C, u16* __restrict__ Cb) {
    const int idx = blockIdx.x * 256 + threadIdx.x;   // over N_TOK*128 float4s
    const int n = idx >> 7, d4 = (idx & 127) << 2;
    const int row = xi[n];
    const int s = n & 511;
    const float4 e = *(const float4*)&emb[(size_t)row * 512 + d4];
    const float4 p = *(const float4*)&pos[(size_t)s * 512 + d4];
    float4 o;
    o.x = 2.f * e.x + p.x; o.y = 2.f * e.y + p.y;
    o.z = 2.f * e.z + p.z; o.w = 2.f * e.w + p.w;
    *(float4*)&C[(size_t)n * 512 + d4] = o;
    u16x4 ob = { f2b(o.x), f2b(o.y), f2b(o.z), f2b(o.w) };
    *(u16x4*)&Cb[(size_t)n * 512 + d4] = ob;
}

// ---------------- weight converts --------------------------------------------
// Q/K weights row-PERMUTED to head-major (dst row h*64+d <- src row h+8*d) so
// the GEMM output is directly [token][h*64+d] — no scatter epilogue needed.
__global__ __launch_bounds__(256) void cvt3_kernel(const float* __restrict__ q,
        const float* __restrict__ k, const float* __restrict__ v,
        u16* __restrict__ dst) {
    const int i = blockIdx.x * 256 + threadIdx.x;      // 1179648 float4s total
    const int l = i / 196608;
    const int rem = i - l * 196608;
    const int m = rem >> 16, r = rem & 65535;
    const int j = r >> 7, col4 = r & 127;              // dst row j, float4 col
    const int srow = (m == 2) ? j : ((j >> 6) | ((j & 63) << 3));
    const float* src = (m == 0 ? q : (m == 1 ? k : v));
    const float4 vv = ((const float4*)src)[(size_t)l * 65536 + srow * 128 + col4];
    u16x4 o = { f2b(vv.x), f2b(vv.y), f2b(vv.z), f2b(vv.w) };
    *(u16x4*)&dst[(size_t)l * 786432 + (size_t)m * 262144 + (size_t)(j * 128 + col4) * 4] = o;
}

// src [Kd][Nd] f32 per layer (z) -> dst [Nd][Kd] bf16
__global__ __launch_bounds__(256) void tcvt_b16_kernel(const float* __restrict__ src,
        u16* __restrict__ dst, int Kd, int Nd) {
    __shared__ u16 t[64][65];
    const int k0 = blockIdx.x * 64, n0 = blockIdx.y * 64;
    const size_t off = (size_t)blockIdx.z * Kd * Nd;
    src += off; dst += off;
    const int cx = threadIdx.x & 63, r0 = threadIdx.x >> 6;
    #pragma unroll
    for (int i = 0; i < 16; ++i) {
        const int r = r0 * 16 + i;
        t[cx][r] = f2b(src[(size_t)(k0 + r) * Nd + n0 + cx]);
    }
    __syncthreads();
    #pragma unroll
    for (int i = 0; i < 16; ++i) {
        const int nn = r0 * 16 + i;
        dst[(size_t)(n0 + nn) * Kd + k0 + cx] = t[nn][cx];
    }
}

// ---------------- bf16 MFMA GEMM: C = A[8192,K] * Bt[N,K]^T -------------------
// BM x 128 tile, BK=64, 8 waves (2Mx4N, 512 thr): per-wave output 64x32,
// acc 4x2 (32 VGPR). Counted-vmcnt 2-buffer pipeline (R8/R10 proven):
// stage(next) -> vmcnt(own stage loads) -> barrier -> compute -> barrier.
enum { EG_QKV3 = 0, EG_F32 = 1, EG_BIAS_F32 = 2, EG_BRELU_B16 = 3 };

template<int BM, int EPI>
__global__ __launch_bounds__(512)
void gemm_bf16(const u16* __restrict__ A, const u16* __restrict__ Bt,
               const float* __restrict__ bias, void* __restrict__ Cout,
               int N, int K) {
    constexpr int AF = BM / 32;              // m-frags per wave (output rows/16)
    constexpr int NLD = BM / 64 + 2;         // gl_lds per wave per stage
    __shared__ u16 As[2][BM * 64];
    __shared__ u16 Bs[2][128 * 64];
    const int tid = threadIdx.x, w = tid >> 6, l = tid & 63;
    const int g = l >> 4, c = l & 15;
    const int wm = w >> 2, wn = w & 3;
    const int bm = blockIdx.x * BM, bn = blockIdx.y * 128;
    const int sr = l >> 3, sc8 = l & 7;

    const f32x4 zero = {0.f, 0.f, 0.f, 0.f};
    f32x4 acc[AF][2];
    #pragma unroll
    for (int i = 0; i < AF; ++i)
        #pragma unroll
        for (int j = 0; j < 2; ++j) acc[i][j] = zero;

    auto stage = [&](int buf, int k0) {
        #pragma unroll
        for (int i = 0; i < BM / 64; ++i) {
            const int rb = w * (BM / 8) + i * 8;
            const int r = rb + sr;
            const int ck = (sc8 ^ (r & 7)) * 8;   // source pre-swizzle (involution)
            gl_lds16(A + (size_t)(bm + r) * K + k0 + ck, &As[buf][rb * 64]);
        }
        #pragma unroll
        for (int i = 0; i < 2; ++i) {
            const int rb = w * 16 + i * 8;
            const int r = rb + sr;
            const int ck = (sc8 ^ (r & 7)) * 8;
            gl_lds16(Bt + (size_t)(bn + r) * K + k0 + ck, &Bs[buf][rb * 64]);
        }
    };

    auto compute = [&](int buf) {
        const char* Ab = (const char*)&As[buf][0];
        const char* Bb = (const char*)&Bs[buf][0];
        #pragma unroll
        for (int ks = 0; ks < 2; ++ks) {
            bf16x8 af[AF], bfv[2];
            #pragma unroll
            for (int q = 0; q < AF; ++q) {
                const int ra = wm * (BM / 2) + q * 16 + c;
                af[q] = *(const bf16x8*)(Ab +
                        ((ra * 128 + ks * 64 + g * 16) ^ ((ra & 7) << 4)));
            }
            #pragma unroll
            for (int q = 0; q < 2; ++q) {
                const int rb2 = wn * 32 + q * 16 + c;
                bfv[q] = *(const bf16x8*)(Bb +
                        ((rb2 * 128 + ks * 64 + g * 16) ^ ((rb2 & 7) << 4)));
            }
            #pragma unroll
            for (int mf = 0; mf < AF; ++mf)
                #pragma unroll
                for (int nf = 0; nf < 2; ++nf)
                    acc[mf][nf] = __builtin_amdgcn_mfma_f32_16x16x32_bf16(
                        af[mf], bfv[nf], acc[mf][nf], 0, 0, 0);
        }
    };

    stage(0, 0);
    int cur = 0;
    for (int k0 = 0; k0 + 64 < K; k0 += 64) {
        stage(cur ^ 1, k0 + 64);              // prefetch flies under compute
        __builtin_amdgcn_sched_barrier(0);
        if (NLD == 4) asm volatile("s_waitcnt vmcnt(4)" ::: "memory");
        else          asm volatile("s_waitcnt vmcnt(3)" ::: "memory");
        __builtin_amdgcn_s_barrier();         // cur buf ready for all waves
        __builtin_amdgcn_sched_barrier(0);
        compute(cur);
        __builtin_amdgcn_sched_barrier(0);
        __builtin_amdgcn_s_barrier();         // all done reading cur before overwrite
        cur ^= 1;
    }
    asm volatile("s_waitcnt vmcnt(0)" ::: "memory");
    __builtin_amdgcn_s_barrier();
    __builtin_amdgcn_sched_barrier(0);
    compute(cur);

    #pragma unroll
    for (int mf = 0; mf < AF; ++mf) {
        #pragma unroll
        for (int nf = 0; nf < 2; ++nf) {
            const int n  = bn + wn * 32 + nf * 16 + c;
            const int m0 = bm + wm * (BM / 2) + mf * 16 + g * 4;
            if (EPI == EG_QKV3) {
                // seg 0/1: Q/K head-major via weight permutation -> coalesced
                // bf16 row write [token][512]. seg 2: V^T.
                u16* o = (u16*)Cout;
                const int seg = n >> 9, nn = n & 511;
                if (seg < 2) {
                    u16* dst = o + (size_t)seg * 4194304;
                    #pragma unroll
                    for (int r = 0; r < 4; ++r)
                        dst[(size_t)(m0 + r) * 512 + nn] = f2b(acc[mf][nf][r]);
                } else {
                    u16* dst = o + (size_t)2 * 4194304;
                    const int h = nn & 7, d = nn >> 3, bb = m0 >> 9, s0 = m0 & 511;
                    u16x4 pk = { f2b(acc[mf][nf][0]), f2b(acc[mf][nf][1]),
                                 f2b(acc[mf][nf][2]), f2b(acc[mf][nf][3]) };
                    *(u16x4*)&dst[((size_t)(h * 16 + bb) * 64 + d) * 512 + s0] = pk;
                }
            } else if (EPI == EG_F32) {
                float* o = (float*)Cout;
                #pragma unroll
                for (int r = 0; r < 4; ++r)
                    o[(size_t)(m0 + r) * N + n] = acc[mf][nf][r];
            } else if (EPI == EG_BIAS_F32) {
                float* o = (float*)Cout;
                const float bv = bias[n];
                #pragma unroll
                for (int r = 0; r < 4; ++r)
                    o[(size_t)(m0 + r) * N + n] = acc[mf][nf][r] + bv;
            } else {  // EG_BRELU_B16
                u16* o = (u16*)Cout;
                const float bv = bias[n];
                #pragma unroll
                for (int r = 0; r < 4; ++r)
                    o[(size_t)(m0 + r) * N + n] = f2b(fmaxf(acc[mf][nf][r] + bv, 0.f));
            }
        }
    }
}

// ---------------- fused bf16-MFMA attention, LDS-staged K/V -------------------
// 8 waves / 128 q-rows per block (grid 512): same per-wave math as R11 (wave
// owns 16 rows end-to-end, bit-identical), but K/V staging + barrier walls are
// amortized over 2x q-rows. launch_bounds(512,2) = 256-reg cap (no spill; R10
// lesson: acc[32]=128 AGPRs needs ~256 unified regs).
__global__ __launch_bounds__(512, 2)
void attn_mfma(const u16* __restrict__ Qb, const u16* __restrict__ Kb,
               const u16* __restrict__ Vt, const float* __restrict__ ga,
               const float* __restrict__ ba, u16* __restrict__ A, float scale) {
    __shared__ __align__(16) u16 KV[2][8192];        // 16KB: K[128][64] or V[64][128]
    __shared__ __align__(16) u16 P[8][16][136];      // [wave][q-row][t-chunk]
    const int bid = blockIdx.x;
    const int hb = bid & 127, qc = bid >> 7;         // grid 512: qc in [0,4)
    const int h = hb >> 4, b = hb & 15;
    const int tid = threadIdx.x, w = tid >> 6, l = tid & 63;
    const int g = l >> 4, c = l & 15;
    const float gah = ga[h], bah = ba[h];
    const size_t tok0 = (size_t)b * SEQ;             // token base for batch b
    const int hoff = h * 64;
    const size_t vtbase = ((size_t)(h * 16 + b)) * 64 * 512;
    const int q0 = qc * 128 + w * 16;                // wave's q rows
    const int swz = (c & 7) << 4;                    // P swizzle
    const int srK = l >> 3, scK = l & 7;             // K staging: 8 lanes/row
    const int srV = l >> 4, scV = l & 15;            // V staging: 16 lanes/row

    // ---- prologue: stage K chunk 0 (buf0); load Q frags ----------------------
    #pragma unroll
    for (int i = 0; i < 2; ++i) {
        const int rb = w * 16 + i * 8;
        const int r = rb + srK;
        gl_lds16(Kb + (tok0 + r) * 512 + hoff + (scK ^ (r & 7)) * 8,
                 &KV[0][rb * 64]);
    }
    const u16* qrow = Qb + (tok0 + q0 + c) * 512 + hoff;
    const bf16x8 qf0 = *(const bf16x8*)(qrow + g * 8);
    const bf16x8 qf1 = *(const bf16x8*)(qrow + 32 + g * 8);
    __syncthreads();                                  // K0 ready

    // ---- QK^T: 4 chunks x 8 tiles; mfma(K,Q) -> lane holds q-row c ----------
    f32x4 acc[32];
    int buf = 0;
    #pragma unroll
    for (int ch = 0; ch < 4; ++ch) {
        if (ch < 3) {
            #pragma unroll
            for (int i = 0; i < 2; ++i) {
                const int rb = w * 16 + i * 8;
                const int r = rb + srK;
                gl_lds16(Kb + (tok0 + (ch + 1) * 128 + r) * 512 + hoff + (scK ^ (r & 7)) * 8,
                         &KV[buf ^ 1][rb * 64]);
            }
        }
        const char* kb = (const char*)&KV[buf][0];
        __builtin_amdgcn_s_setprio(1);
        #pragma unroll
        for (int tt = 0; tt < 8; ++tt) {
            const int r = tt * 16 + c;
            const int sx = (r & 7) << 4;
            const char* rowp = kb + r * 128;
            const bf16x8 kf0 = *(const bf16x8*)(rowp + ((g * 16) ^ sx));
            const bf16x8 kf1 = *(const bf16x8*)(rowp + ((64 + g * 16) ^ sx));
            f32x4 z = {0.f, 0.f, 0.f, 0.f};
            z = __builtin_amdgcn_mfma_f32_16x16x32_bf16(kf0, qf0, z, 0, 0, 0);
            z = __builtin_amdgcn_mfma_f32_16x16x32_bf16(kf1, qf1, z, 0, 0, 0);
            acc[ch * 8 + tt] = z;
        }
        __builtin_amdgcn_s_setprio(0);
        if (ch < 3) { __syncthreads(); buf ^= 1; }
    }

    // ---- stage V chunk 0 into KV[0] ------------------------------------------
    #pragma unroll
    for (int i = 0; i < 2; ++i) {
        const int db = w * 8 + i * 4;
        const int d = db + srV;
        gl_lds16(Vt + vtbase + (size_t)d * 512 + (scV ^ (d & 7)) * 8,
                 &KV[0][db * 128]);
    }

    // ---- row stats for q-row c (overlaps V0 staging) -------------------------
    float sm = 0.f, sq = 0.f;
    #pragma unroll
    for (int t = 0; t < 32; ++t)
        #pragma unroll
        for (int r = 0; r < 4; ++r) {
            const float v = acc[t][r];
            sm += v; sq = fmaf(v, v, sq);
        }
    sm += __shfl_xor(sm, 16); sm += __shfl_xor(sm, 32);
    sq += __shfl_xor(sq, 16); sq += __shfl_xor(sq, 32);

    const float LOG2E = 1.4426950408889634f;
    const float S  = sm * scale;
    const float Qq = sq * scale * scale;
    const float mu = S * (1.f / 512.f);
    const float var = (Qq - 512.f * mu * mu) * (1.f / 511.f);
    const float rg = rsqrtf(var + 1e-8f) * gah;
    const float A2 = scale * rg * LOG2E;
    const float B2 = (bah - mu * rg) * LOG2E;

    __syncthreads();                                  // V0 ready

    // ---- PV: per chunk exp -> P_lds (wave-private) -> MFMA vs LDS V ---------
    float se = 0.f;
    f32x4 oacc[4];
    #pragma unroll
    for (int dt = 0; dt < 4; ++dt) oacc[dt] = (f32x4){0.f, 0.f, 0.f, 0.f};

    int vbuf = 0;
    #pragma unroll
    for (int ch = 0; ch < 4; ++ch) {
        if (ch < 3) {
            #pragma unroll
            for (int i = 0; i < 2; ++i) {
                const int db = w * 8 + i * 4;
                const int d = db + srV;
                gl_lds16(Vt + vtbase + (size_t)d * 512 + (ch + 1) * 128 + (scV ^ (d & 7)) * 8,
                         &KV[vbuf ^ 1][db * 128]);
            }
        }
        char* pbase = (char*)&P[w][0][0];
        #pragma unroll
        for (int tt = 0; tt < 8; ++tt) {
            const int t = ch * 8 + tt;
            float p0 = exp2f(fmaf(acc[t][0], A2, B2));
            float p1 = exp2f(fmaf(acc[t][1], A2, B2));
            float p2 = exp2f(fmaf(acc[t][2], A2, B2));
            float p3 = exp2f(fmaf(acc[t][3], A2, B2));
            se += (p0 + p1) + (p2 + p3);
            u16x4 pk = { f2b(p0), f2b(p1), f2b(p2), f2b(p3) };
            *(u16x4*)(pbase + c * 272 + ((tt * 32 + g * 8) ^ swz)) = pk;
        }
        const char* vb = (const char*)&KV[vbuf][0];
        __builtin_amdgcn_s_setprio(1);
        #pragma unroll
        for (int ks = 0; ks < 4; ++ks) {
            const bf16x8 pf = *(const bf16x8*)(pbase + c * 272 + ((ks * 64 + g * 16) ^ swz));
            #pragma unroll
            for (int dt = 0; dt < 4; ++dt) {
                const int d = dt * 16 + c;
                const bf16x8 vf = *(const bf16x8*)(vb + d * 256 +
                        ((ks * 64 + g * 16) ^ ((d & 7) << 4)));
                oacc[dt] = __builtin_amdgcn_mfma_f32_16x16x32_bf16(pf, vf, oacc[dt], 0, 0, 0);
            }
        }
        __builtin_amdgcn_s_setprio(0);
        if (ch < 3) { __syncthreads(); vbuf ^= 1; }
    }

    // ---- softmax denom + output ----------------------------------------------
    se += __shfl_xor(se, 16); se += __shfl_xor(se, 32);
    const float inv = 1.f / se;          // for q-row c
    float iv[4];
    #pragma unroll
    for (int r = 0; r < 4; ++r) iv[r] = __shfl(inv, g * 4 + r);
    #pragma unroll
    for (int dt = 0; dt < 4; ++dt)
        #pragma unroll
        for (int r = 0; r < 4; ++r)
            A[((size_t)(b * 512 + q0 + g * 4 + r)) * 512 + h * 64 + dt * 16 + c] =
                f2b(oacc[dt][r] * iv[r]);
}

// ---------------- LayerNorm(X + R); optional outputs -------------------------
__global__ __launch_bounds__(256)
void ln_res_kernel(const float* __restrict__ X, const float* __restrict__ R,
                   const float* __restrict__ gp, const float* __restrict__ bp,
                   int lidx, float* __restrict__ Y, u16* __restrict__ Yb,
                   float* __restrict__ Cacc, u16* __restrict__ Cb) {
    const int tid = threadIdx.x, w = tid >> 6, l = tid & 63;
    const size_t row = (size_t)blockIdx.x * 4 + w;
    const float g = gp[lidx], bb = bp[lidx];
    const float* x = X + row * 512;
    const float* r = R + row * 512;
    float v[8];
    const float4 a0 = *(const float4*)&x[l * 8], a1 = *(const float4*)&x[l * 8 + 4];
    const float4 r0 = *(const float4*)&r[l * 8], r1 = *(const float4*)&r[l * 8 + 4];
    v[0] = a0.x + r0.x; v[1] = a0.y + r0.y; v[2] = a0.z + r0.z; v[3] = a0.w + r0.w;
    v[4] = a1.x + r1.x; v[5] = a1.y + r1.y; v[6] = a1.z + r1.z; v[7] = a1.w + r1.w;
    float s = 0.f, sq = 0.f;
    #pragma unroll
    for (int i = 0; i < 8; ++i) { s += v[i]; sq = fmaf(v[i], v[i], sq); }
    #pragma unroll
    for (int o = 1; o < 64; o <<= 1) { s += __shfl_xor(s, o); sq += __shfl_xor(sq, o); }
    const float mu   = s * (1.f / 512.f);
    const float var  = (sq - 512.f * mu * mu) * (1.f / 511.f);
    const float rstd = rsqrtf(var + 1e-8f);
    float y[8];
    #pragma unroll
    for (int i = 0; i < 8; ++i) y[i] = fmaf((v[i] - mu) * rstd, g, bb);
    if (Y) {
        *(float4*)&Y[row * 512 + l * 8]     = *(float4*)&y[0];
        *(float4*)&Y[row * 512 + l * 8 + 4] = *(float4*)&y[4];
    }
    if (Yb) {
        u16x8 yb;
        #pragma unroll
        for (int i = 0; i < 8; ++i) yb[i] = f2b(y[i]);
        *(u16x8*)&Yb[row * 512 + l * 8] = yb;
    }
    if (Cacc) {
        float cv[8];
        float4 c0 = *(float4*)&Cacc[row * 512 + l * 8];
        float4 c1 = *(float4*)&Cacc[row * 512 + l * 8 + 4];
        cv[0] = c0.x + y[0]; cv[1] = c0.y + y[1]; cv[2] = c0.z + y[2]; cv[3] = c0.w + y[3];
        cv[4] = c1.x + y[4]; cv[5] = c1.y + y[5]; cv[6] = c1.z + y[6]; cv[7] = c1.w + y[7];
        *(float4*)&Cacc[row * 512 + l * 8]     = *(float4*)&cv[0];
        *(float4*)&Cacc[row * 512 + l * 8 + 4] = *(float4*)&cv[4];
        u16x8 cb;
        #pragma unroll
        for (int i = 0; i < 8; ++i) cb[i] = f2b(cv[i]);
        *(u16x8*)&Cb[row * 512 + l * 8] = cb;
    }
}

// ---------------- final head: x9 = X8 @ V_e ----------------------------------
__global__ __launch_bounds__(256)
void fin_ve_kernel(const float* __restrict__ X8, const float* __restrict__ Ve,
                   float* __restrict__ x9) {
    const int tid = threadIdx.x, w = tid >> 6, l = tid & 63;
    const size_t row = (size_t)blockIdx.x * 4 + w;
    const float* x = X8 + row * 512;
    float s = 0.f;
    #pragma unroll
    for (int i = 0; i < 8; ++i) s = fmaf(x[l * 8 + i], Ve[l * 8 + i], s);
    #pragma unroll
    for (int o = 1; o < 64; o <<= 1) s += __shfl_xor(s, o);
    if (l == 0) x9[row] = s;
}

// ---------------- fin_vd split-K: zp[sc][b][c] = sum_{s in chunk} x9*Vd -------
__global__ __launch_bounds__(256)
void fin_vd_part(const float* __restrict__ x9, const float* __restrict__ Vd,
                 float* __restrict__ zp) {
    __shared__ float xs[16][64];
    const int tid = threadIdx.x;
    const int c = blockIdx.x * 256 + tid;
    const int sc = blockIdx.y, s0 = sc * 64;
    #pragma unroll
    for (int p = 0; p < 4; ++p) {
        const int idx = p * 256 + tid;           // over [16][64]
        xs[idx >> 6][idx & 63] = x9[(idx >> 6) * 512 + s0 + (idx & 63)];
    }
    __syncthreads();
    float acc[16];
    #pragma unroll
    for (int b = 0; b < 16; ++b) acc[b] = 0.f;
    if (c < NCLS) {
        for (int s = 0; s < 64; ++s) {
            const float vd = Vd[(size_t)(s0 + s) * NCLS + c];
            #pragma unroll
            for (int b = 0; b < 16; ++b) acc[b] = fmaf(xs[b][s], vd, acc[b]);
        }
    }
    #pragma unroll
    for (int b = 0; b < 16; ++b)
        zp[((size_t)sc * 16 + b) * 10240 + c] = acc[b];
}

// ---------------- final norm (ddof=1 over 10000) + softmax -------------------
__global__ __launch_bounds__(256)
void fin_sm_kernel(const float* __restrict__ zp, const float* __restrict__ gp,
                   const float* __restrict__ bp, float* __restrict__ out) {
    __shared__ float zs[NCLS];
    __shared__ float red[4];
    __shared__ float red2[4];
    const int b = blockIdx.x, tid = threadIdx.x, w = tid >> 6, l = tid & 63;
    float s = 0.f, sq = 0.f;
    for (int i = tid; i < NCLS; i += 256) {
        float v = 0.f;
        #pragma unroll
        for (int sc = 0; sc < VD_SC; ++sc)
            v += zp[((size_t)sc * 16 + b) * 10240 + i];
        zs[i] = v; s += v; sq = fmaf(v, v, sq);
    }
    #pragma unroll
    for (int o = 1; o < 64; o <<= 1) { s += __shfl_xor(s, o); sq += __shfl_xor(sq, o); }
    if (l == 0) { red[w] = s; red2[w] = sq; }
    __syncthreads();
    s  = red[0] + red[1] + red[2] + red[3];
    sq = red2[0] + red2[1] + red2[2] + red2[3];
    const float mu   = s / 10000.f;
    const float var  = (sq - 10000.f * mu * mu) / 9999.f;
    const float rstd = rsqrtf(var + 1e-8f);
    const float g = gp[0], be = bp[0];
    __syncthreads();
    float mx = -1e30f;
    for (int i = tid; i < NCLS; i += 256) {
        const float e = fmaf((zs[i] - mu) * rstd, g, be);
        zs[i] = e; mx = fmaxf(mx, e);
    }
    #pragma unroll
    for (int o = 1; o < 64; o <<= 1) mx = fmaxf(mx, __shfl_xor(mx, o));
    if (l == 0) red[w] = mx;
    __syncthreads();
    mx = fmaxf(fmaxf(red[0], red[1]), fmaxf(red[2], red[3]));
    float es = 0.f;
    for (int i = tid; i < NCLS; i += 256) {
        const float p = expf(zs[i] - mx);
        zs[i] = p; es += p;
    }
    #pragma unroll
    for (int o = 1; o < 64; o <<= 1) es += __shfl_xor(es, o);
    if (l == 0) red2[w] = es;
    __syncthreads();
    es = red2[0] + red2[1] + red2[2] + red2[3];
    const float inv = 1.f / es;
    for (int i = tid; i < NCLS; i += 256) out[(size_t)b * NCLS + i] = zs[i] * inv;
}

// =============================================================================
extern "C" void kernel_launch(void* const* d_in, const int* in_sizes, int n_in,
                              void* d_out, int out_size, void* d_ws, size_t ws_size,
                              hipStream_t stream) {
    (void)in_sizes; (void)n_in; (void)out_size; (void)ws_size;
    const int*   xi  = (const int*)d_in[0];
    const float* emb = (const float*)d_in[1];
    const float* WQ  = (const float*)d_in[2];
    const float* WK  = (const float*)d_in[3];
    const float* WV  = (const float*)d_in[4];
    const float* WO  = (const float*)d_in[5];
    const float* W1  = (const float*)d_in[6];
    const float* b1  = (const float*)d_in[7];
    const float* W2  = (const float*)d_in[8];
    const float* b2  = (const float*)d_in[9];
    const float* ga  = (const float*)d_in[10];
    const float* ba  = (const float*)d_in[11];
    const float* g1  = (const float*)d_in[12];
    const float* be1 = (const float*)d_in[13];
    const float* g2  = (const float*)d_in[14];
    const float* be2 = (const float*)d_in[15];
    const float* Ve  = (const float*)d_in[16];
    const float* Vd  = (const float*)d_in[17];
    const float* gf  = (const float*)d_in[18];
    const float* bf  = (const float*)d_in[19];
    float* out = (float*)d_out;

    // ---------------- workspace layout ----------------
    float* ws  = (float*)d_ws;
    float* pos = ws;                        // 262144 f
    float* C   = pos + 262144;              // 4M f
    float* X2  = C   + 4194304;
    float* OUT = X2  + 4194304;
    float* PF  = OUT + 4194304;
    u16* ub = (u16*)(PF + 4194304);
    u16* Cb  = ub;  ub += 4194304;          // bf16 carry [8192][512]
    u16* X2b = ub;  ub += 4194304;          // bf16 x2    [8192][512]
    u16* Qbf = ub;  ub += 4194304;          // [8192][512] head-major cols; K at +4M, Vt at +8M
    u16* Kbf = ub;  ub += 4194304;
    u16* Vtb = ub;  ub += 4194304;          // [H*16][64][512]
    u16* Abf = ub;  ub += 4194304;          // attn out bf16 [8192][512]
    u16* Hb  = Qbf;                         // FF hidden [8192][2048] aliases Q|K|Vt|A
    float* zp = (float*)Vtb;                // fin_vd partials [8][16][10240] (Vtb dead)
    u16* WQKVb = ub; ub += 4718592;         // 6 x [1536][512]
    u16* WOt = ub; ub += 1572864;           // 6 x [512][512] (transposed)
    u16* W1t = ub; ub += 6291456;           // 6 x [2048][512] (transposed)
    u16* W2t = ub; ub += 6291456;           // 6 x [512][2048] (transposed)
    float* x9 = (float*)ub;                 // 8192 f

    pos_kernel<<<16, 512, 0, stream>>>(pos);
    embed_kernel<<<4096, 256, 0, stream>>>(xi, emb, pos, C, Cb);

    cvt3_kernel<<<4608, 256, 0, stream>>>(WQ, WK, WV, WQKVb);
    tcvt_b16_kernel<<<dim3(8,  8, 6), 256, 0, stream>>>(WO, WOt, 512, 512);
    tcvt_b16_kernel<<<dim3(8, 32, 6), 256, 0, stream>>>(W1, W1t, 512, 2048);
    tcvt_b16_kernel<<<dim3(32, 8, 6), 256, 0, stream>>>(W2, W2t, 2048, 512);

    const float scale = 1.0f / sqrtf(512.0f);

    for (int l = 0; l < NLAYER; ++l) {
        const u16* wqkv = WQKVb + (size_t)l * 786432;
        const u16* wo = WOt + (size_t)l * 262144;
        const u16* w1 = W1t + (size_t)l * 1048576;
        const u16* w2 = W2t + (size_t)l * 1048576;

        gemm_bf16<128, EG_QKV3>     <<<dim3(64, 12), 512, 0, stream>>>(Cb, wqkv, nullptr, Qbf, 1536, 512);
        attn_mfma                   <<<512, 512, 0, stream>>>(Qbf, Kbf, Vtb, ga + l*8, ba + l*8, Abf, scale);
        gemm_bf16<64, EG_F32>       <<<dim3(128, 4), 512, 0, stream>>>(Abf, wo, nullptr, PF, 512, 512);
        ln_res_kernel               <<<2048, 256, 0, stream>>>(PF, C, g1, be1, l, X2, X2b, nullptr, nullptr);
        gemm_bf16<128, EG_BRELU_B16><<<dim3(64, 16), 512, 0, stream>>>(X2b, w1, b1 + l*2048, Hb, 2048, 512);
        gemm_bf16<64, EG_BIAS_F32>  <<<dim3(128, 4), 512, 0, stream>>>(Hb, w2, b2 + l*512, PF, 512, 2048);
        ln_res_kernel               <<<2048, 256, 0, stream>>>(PF, X2, g2, be2, l,
                                                               (l == NLAYER - 1) ? OUT : nullptr,
                                                               nullptr, C, Cb);
    }

    fin_ve_kernel<<<2048, 256, 0, stream>>>(OUT, Ve, x9);
    fin_vd_part<<<dim3(40, VD_SC), 256, 0, stream>>>(x9, Vd, zp);
    fin_sm_kernel<<<16, 256, 0, stream>>>(zp, gf, bf, out);
}

// Round 13
// 860.607 us; speedup vs baseline: 1.0087x; 1.0087x over previous
//
#include <hip/hip_runtime.h>
#include <hip/hip_bf16.h>
#include <math.h>

#define N_TOK 8192
#define DMODEL 512
#define NHEAD 8
#define HDIM 64
#define SEQ 512
#define BATCH 16
#define FFDIM 2048
#define NLAYER 6
#define NCLS 10000
#define VD_SC 8          // s-chunks for fin_vd split-K

typedef unsigned short u16;
typedef __attribute__((ext_vector_type(8))) short bf16x8;
typedef __attribute__((ext_vector_type(8))) unsigned short u16x8;
typedef __attribute__((ext_vector_type(4))) unsigned short u16x4;
typedef __attribute__((ext_vector_type(4))) float f32x4;

__device__ __forceinline__ u16 f2b(float x) {   // RNE f32 -> bf16 (finite inputs)
    unsigned int u = __float_as_uint(x);
    u += 0x7fffu + ((u >> 16) & 1u);
    return (u16)(u >> 16);
}

__device__ __forceinline__ void gl_lds16(const void* g, void* l) {
    __builtin_amdgcn_global_load_lds(
        (const __attribute__((address_space(1))) unsigned int*)g,
        (__attribute__((address_space(3))) unsigned int*)l, 16, 0, 0);
}

// ---------------- positional table: fp64 rotation recurrence ------------------
__global__ __launch_bounds__(512) void pos_kernel(float* __restrict__ pos) {
    const int i = threadIdx.x;
    const int s0 = blockIdx.x * 32;
    const double bse = pow(10000.0, -(double)(i & ~1) / 512.0);
    const double cb = cos(bse), sb = sin(bse);
    const double a0 = (double)s0 * bse;
    double sn = sin(a0), cs = cos(a0);
    const bool odd = i & 1;
    for (int k = 0; k < 32; ++k) {
        pos[(size_t)(s0 + k) * 512 + i] = (float)(odd ? cs : sn);
        const double ns = sn * cb + cs * sb;
        cs = cs * cb - sn * sb;
        sn = ns;
    }
}

// ---------------- embedding: C = 2*emb[x] + pos (f32 + bf16 copies) ----------
__global__ __launch_bounds__(256) void embed_kernel(const int* __restrict__ xi,
        const float* __restrict__ emb, const float* __restrict__ pos,
        float* __restrict__ C, u16* __restrict__ Cb) {
    const int idx = blockIdx.x * 256 + threadIdx.x;   // over N_TOK*128 float4s
    const int n = idx >> 7, d4 = (idx & 127) << 2;
    const int row = xi[n];
    const int s = n & 511;
    const float4 e = *(const float4*)&emb[(size_t)row * 512 + d4];
    const float4 p = *(const float4*)&pos[(size_t)s * 512 + d4];
    float4 o;
    o.x = 2.f * e.x + p.x; o.y = 2.f * e.y + p.y;
    o.z = 2.f * e.z + p.z; o.w = 2.f * e.w + p.w;
    *(float4*)&C[(size_t)n * 512 + d4] = o;
    u16x4 ob = { f2b(o.x), f2b(o.y), f2b(o.z), f2b(o.w) };
    *(u16x4*)&Cb[(size_t)n * 512 + d4] = ob;
}

// ---------------- weight converts --------------------------------------------
// Q/K weights row-PERMUTED to head-major (dst row h*64+d <- src row h+8*d) so
// the GEMM output is directly [token][h*64+d] — no scatter epilogue needed.
__global__ __launch_bounds__(256) void cvt3_kernel(const float* __restrict__ q,
        const float* __restrict__ k, const float* __restrict__ v,
        u16* __restrict__ dst) {
    const int i = blockIdx.x * 256 + threadIdx.x;      // 1179648 float4s total
    const int l = i / 196608;
    const int rem = i - l * 196608;
    const int m = rem >> 16, r = rem & 65535;
    const int j = r >> 7, col4 = r & 127;              // dst row j, float4 col
    const int srow = (m == 2) ? j : ((j >> 6) | ((j & 63) << 3));
    const float* src = (m == 0 ? q : (m == 1 ? k : v));
    const float4 vv = ((const float4*)src)[(size_t)l * 65536 + srow * 128 + col4];
    u16x4 o = { f2b(vv.x), f2b(vv.y), f2b(vv.z), f2b(vv.w) };
    *(u16x4*)&dst[(size_t)l * 786432 + (size_t)m * 262144 + (size_t)(j * 128 + col4) * 4] = o;
}

// src [Kd][Nd] f32 per layer (z) -> dst [Nd][Kd] bf16
__global__ __launch_bounds__(256) void tcvt_b16_kernel(const float* __restrict__ src,
        u16* __restrict__ dst, int Kd, int Nd) {
    __shared__ u16 t[64][65];
    const int k0 = blockIdx.x * 64, n0 = blockIdx.y * 64;
    const size_t off = (size_t)blockIdx.z * Kd * Nd;
    src += off; dst += off;
    const int cx = threadIdx.x & 63, r0 = threadIdx.x >> 6;
    #pragma unroll
    for (int i = 0; i < 16; ++i) {
        const int r = r0 * 16 + i;
        t[cx][r] = f2b(src[(size_t)(k0 + r) * Nd + n0 + cx]);
    }
    __syncthreads();
    #pragma unroll
    for (int i = 0; i < 16; ++i) {
        const int nn = r0 * 16 + i;
        dst[(size_t)(n0 + nn) * Kd + k0 + cx] = t[nn][cx];
    }
}

// ---------------- bf16 MFMA GEMM: C = A[8192,K] * Bt[N,K]^T (+ residual) ------
// BM x 128 tile, BK=64, 8 waves (2Mx4N, 512 thr). Counted-vmcnt 2-buffer:
// stage(next) -> vmcnt(own stage loads) -> barrier -> compute -> barrier.
// EG_F32 / EG_BIAS_F32 fuse the residual add (o = acc [+bias] + Cres) so the
// following LayerNorm reads ONE tensor instead of two (bit-identical f32 adds).
enum { EG_QKV3 = 0, EG_F32 = 1, EG_BIAS_F32 = 2, EG_BRELU_B16 = 3 };

template<int BM, int EPI>
__global__ __launch_bounds__(512)
void gemm_bf16(const u16* __restrict__ A, const u16* __restrict__ Bt,
               const float* __restrict__ bias, const float* __restrict__ Cres,
               void* __restrict__ Cout, int N, int K) {
    constexpr int AF = BM / 32;              // m-frags per wave (output rows/16)
    constexpr int NLD = BM / 64 + 2;         // gl_lds per wave per stage
    __shared__ u16 As[2][BM * 64];
    __shared__ u16 Bs[2][128 * 64];
    const int tid = threadIdx.x, w = tid >> 6, l = tid & 63;
    const int g = l >> 4, c = l & 15;
    const int wm = w >> 2, wn = w & 3;
    const int bm = blockIdx.x * BM, bn = blockIdx.y * 128;
    const int sr = l >> 3, sc8 = l & 7;

    const f32x4 zero = {0.f, 0.f, 0.f, 0.f};
    f32x4 acc[AF][2];
    #pragma unroll
    for (int i = 0; i < AF; ++i)
        #pragma unroll
        for (int j = 0; j < 2; ++j) acc[i][j] = zero;

    auto stage = [&](int buf, int k0) {
        #pragma unroll
        for (int i = 0; i < BM / 64; ++i) {
            const int rb = w * (BM / 8) + i * 8;
            const int r = rb + sr;
            const int ck = (sc8 ^ (r & 7)) * 8;   // source pre-swizzle (involution)
            gl_lds16(A + (size_t)(bm + r) * K + k0 + ck, &As[buf][rb * 64]);
        }
        #pragma unroll
        for (int i = 0; i < 2; ++i) {
            const int rb = w * 16 + i * 8;
            const int r = rb + sr;
            const int ck = (sc8 ^ (r & 7)) * 8;
            gl_lds16(Bt + (size_t)(bn + r) * K + k0 + ck, &Bs[buf][rb * 64]);
        }
    };

    auto compute = [&](int buf) {
        const char* Ab = (const char*)&As[buf][0];
        const char* Bb = (const char*)&Bs[buf][0];
        #pragma unroll
        for (int ks = 0; ks < 2; ++ks) {
            bf16x8 af[AF], bfv[2];
            #pragma unroll
            for (int q = 0; q < AF; ++q) {
                const int ra = wm * (BM / 2) + q * 16 + c;
                af[q] = *(const bf16x8*)(Ab +
                        ((ra * 128 + ks * 64 + g * 16) ^ ((ra & 7) << 4)));
            }
            #pragma unroll
            for (int q = 0; q < 2; ++q) {
                const int rb2 = wn * 32 + q * 16 + c;
                bfv[q] = *(const bf16x8*)(Bb +
                        ((rb2 * 128 + ks * 64 + g * 16) ^ ((rb2 & 7) << 4)));
            }
            #pragma unroll
            for (int mf = 0; mf < AF; ++mf)
                #pragma unroll
                for (int nf = 0; nf < 2; ++nf)
                    acc[mf][nf] = __builtin_amdgcn_mfma_f32_16x16x32_bf16(
                        af[mf], bfv[nf], acc[mf][nf], 0, 0, 0);
        }
    };

    stage(0, 0);
    int cur = 0;
    for (int k0 = 0; k0 + 64 < K; k0 += 64) {
        stage(cur ^ 1, k0 + 64);              // prefetch flies under compute
        __builtin_amdgcn_sched_barrier(0);
        if (NLD == 4) asm volatile("s_waitcnt vmcnt(4)" ::: "memory");
        else          asm volatile("s_waitcnt vmcnt(3)" ::: "memory");
        __builtin_amdgcn_s_barrier();         // cur buf ready for all waves
        __builtin_amdgcn_sched_barrier(0);
        compute(cur);
        __builtin_amdgcn_sched_barrier(0);
        __builtin_amdgcn_s_barrier();         // all done reading cur before overwrite
        cur ^= 1;
    }
    asm volatile("s_waitcnt vmcnt(0)" ::: "memory");
    __builtin_amdgcn_s_barrier();
    __builtin_amdgcn_sched_barrier(0);
    compute(cur);

    #pragma unroll
    for (int mf = 0; mf < AF; ++mf) {
        #pragma unroll
        for (int nf = 0; nf < 2; ++nf) {
            const int n  = bn + wn * 32 + nf * 16 + c;
            const int m0 = bm + wm * (BM / 2) + mf * 16 + g * 4;
            if (EPI == EG_QKV3) {
                // seg 0/1: Q/K head-major via weight permutation -> coalesced
                // bf16 row write [token][512]. seg 2: V^T.
                u16* o = (u16*)Cout;
                const int seg = n >> 9, nn = n & 511;
                if (seg < 2) {
                    u16* dst = o + (size_t)seg * 4194304;
                    #pragma unroll
                    for (int r = 0; r < 4; ++r)
                        dst[(size_t)(m0 + r) * 512 + nn] = f2b(acc[mf][nf][r]);
                } else {
                    u16* dst = o + (size_t)2 * 4194304;
                    const int h = nn & 7, d = nn >> 3, bb = m0 >> 9, s0 = m0 & 511;
                    u16x4 pk = { f2b(acc[mf][nf][0]), f2b(acc[mf][nf][1]),
                                 f2b(acc[mf][nf][2]), f2b(acc[mf][nf][3]) };
                    *(u16x4*)&dst[((size_t)(h * 16 + bb) * 64 + d) * 512 + s0] = pk;
                }
            } else if (EPI == EG_F32) {
                float* o = (float*)Cout;
                #pragma unroll
                for (int r = 0; r < 4; ++r)
                    o[(size_t)(m0 + r) * N + n] =
                        acc[mf][nf][r] + Cres[(size_t)(m0 + r) * N + n];
            } else if (EPI == EG_BIAS_F32) {
                float* o = (float*)Cout;
                const float bv = bias[n];
                #pragma unroll
                for (int r = 0; r < 4; ++r)
                    o[(size_t)(m0 + r) * N + n] =
                        (acc[mf][nf][r] + bv) + Cres[(size_t)(m0 + r) * N + n];
            } else {  // EG_BRELU_B16
                u16* o = (u16*)Cout;
                const float bv = bias[n];
                #pragma unroll
                for (int r = 0; r < 4; ++r)
                    o[(size_t)(m0 + r) * N + n] = f2b(fmaxf(acc[mf][nf][r] + bv, 0.f));
            }
        }
    }
}

// ---------------- fused bf16-MFMA attention, LDS-staged K/V (R11 version) -----
// Q/K layout [B*S tokens][512] with head-major cols (h*64+d). 4 waves/64 rows.
// launch_bounds(256,2): acc[32]=128 AGPRs needs ~256 unified regs (R10 lesson).
__global__ __launch_bounds__(256, 2)
void attn_mfma(const u16* __restrict__ Qb, const u16* __restrict__ Kb,
               const u16* __restrict__ Vt, const float* __restrict__ ga,
               const float* __restrict__ ba, u16* __restrict__ A, float scale) {
    __shared__ __align__(16) u16 KV[2][8192];        // 16KB: K[128][64] or V[64][128]
    __shared__ __align__(16) u16 P[4][16][136];      // [wave][q-row][t-chunk]
    const int bid = blockIdx.x;
    const int hb = bid & 127, qc = bid >> 7;         // grid 1024
    const int h = hb >> 4, b = hb & 15;
    const int tid = threadIdx.x, w = tid >> 6, l = tid & 63;
    const int g = l >> 4, c = l & 15;
    const float gah = ga[h], bah = ba[h];
    const size_t tok0 = (size_t)b * SEQ;             // token base for batch b
    const int hoff = h * 64;
    const size_t vtbase = ((size_t)(h * 16 + b)) * 64 * 512;
    const int q0 = qc * 64 + w * 16;                 // wave's q rows
    const int swz = (c & 7) << 4;                    // P swizzle
    const int srK = l >> 3, scK = l & 7;             // K staging: 8 lanes/row
    const int srV = l >> 4, scV = l & 15;            // V staging: 16 lanes/row

    // ---- prologue: stage K chunk 0 (buf0); load Q frags ----------------------
    #pragma unroll
    for (int i = 0; i < 4; ++i) {
        const int rb = w * 32 + i * 8;
        const int r = rb + srK;
        gl_lds16(Kb + (tok0 + r) * 512 + hoff + (scK ^ (r & 7)) * 8,
                 &KV[0][rb * 64]);
    }
    const u16* qrow = Qb + (tok0 + q0 + c) * 512 + hoff;
    const bf16x8 qf0 = *(const bf16x8*)(qrow + g * 8);
    const bf16x8 qf1 = *(const bf16x8*)(qrow + 32 + g * 8);
    __syncthreads();                                  // K0 ready

    // ---- QK^T: 4 chunks x 8 tiles; mfma(K,Q) -> lane holds q-row c ----------
    f32x4 acc[32];
    int buf = 0;
    #pragma unroll
    for (int ch = 0; ch < 4; ++ch) {
        if (ch < 3) {
            #pragma unroll
            for (int i = 0; i < 4; ++i) {
                const int rb = w * 32 + i * 8;
                const int r = rb + srK;
                gl_lds16(Kb + (tok0 + (ch + 1) * 128 + r) * 512 + hoff + (scK ^ (r & 7)) * 8,
                         &KV[buf ^ 1][rb * 64]);
            }
        }
        const char* kb = (const char*)&KV[buf][0];
        __builtin_amdgcn_s_setprio(1);
        #pragma unroll
        for (int tt = 0; tt < 8; ++tt) {
            const int r = tt * 16 + c;
            const int sx = (r & 7) << 4;
            const char* rowp = kb + r * 128;
            const bf16x8 kf0 = *(const bf16x8*)(rowp + ((g * 16) ^ sx));
            const bf16x8 kf1 = *(const bf16x8*)(rowp + ((64 + g * 16) ^ sx));
            f32x4 z = {0.f, 0.f, 0.f, 0.f};
            z = __builtin_amdgcn_mfma_f32_16x16x32_bf16(kf0, qf0, z, 0, 0, 0);
            z = __builtin_amdgcn_mfma_f32_16x16x32_bf16(kf1, qf1, z, 0, 0, 0);
            acc[ch * 8 + tt] = z;
        }
        __builtin_amdgcn_s_setprio(0);
        if (ch < 3) { __syncthreads(); buf ^= 1; }
    }

    // ---- stage V chunk 0 into KV[0] ------------------------------------------
    #pragma unroll
    for (int i = 0; i < 4; ++i) {
        const int db = w * 16 + i * 4;
        const int d = db + srV;
        gl_lds16(Vt + vtbase + (size_t)d * 512 + (scV ^ (d & 7)) * 8,
                 &KV[0][db * 128]);
    }

    // ---- row stats for q-row c (overlaps V0 staging) -------------------------
    float sm = 0.f, sq = 0.f;
    #pragma unroll
    for (int t = 0; t < 32; ++t)
        #pragma unroll
        for (int r = 0; r < 4; ++r) {
            const float v = acc[t][r];
            sm += v; sq = fmaf(v, v, sq);
        }
    sm += __shfl_xor(sm, 16); sm += __shfl_xor(sm, 32);
    sq += __shfl_xor(sq, 16); sq += __shfl_xor(sq, 32);

    const float LOG2E = 1.4426950408889634f;
    const float S  = sm * scale;
    const float Qq = sq * scale * scale;
    const float mu = S * (1.f / 512.f);
    const float var = (Qq - 512.f * mu * mu) * (1.f / 511.f);
    const float rg = rsqrtf(var + 1e-8f) * gah;
    const float A2 = scale * rg * LOG2E;
    const float B2 = (bah - mu * rg) * LOG2E;

    __syncthreads();                                  // V0 ready

    // ---- PV: per chunk exp -> P_lds (wave-private) -> MFMA vs LDS V ---------
    float se = 0.f;
    f32x4 oacc[4];
    #pragma unroll
    for (int dt = 0; dt < 4; ++dt) oacc[dt] = (f32x4){0.f, 0.f, 0.f, 0.f};

    int vbuf = 0;
    #pragma unroll
    for (int ch = 0; ch < 4; ++ch) {
        if (ch < 3) {
            #pragma unroll
            for (int i = 0; i < 4; ++i) {
                const int db = w * 16 + i * 4;
                const int d = db + srV;
                gl_lds16(Vt + vtbase + (size_t)d * 512 + (ch + 1) * 128 + (scV ^ (d & 7)) * 8,
                         &KV[vbuf ^ 1][db * 128]);
            }
        }
        char* pbase = (char*)&P[w][0][0];
        #pragma unroll
        for (int tt = 0; tt < 8; ++tt) {
            const int t = ch * 8 + tt;
            float p0 = exp2f(fmaf(acc[t][0], A2, B2));
            float p1 = exp2f(fmaf(acc[t][1], A2, B2));
            float p2 = exp2f(fmaf(acc[t][2], A2, B2));
            float p3 = exp2f(fmaf(acc[t][3], A2, B2));
            se += (p0 + p1) + (p2 + p3);
            u16x4 pk = { f2b(p0), f2b(p1), f2b(p2), f2b(p3) };
            *(u16x4*)(pbase + c * 272 + ((tt * 32 + g * 8) ^ swz)) = pk;
        }
        const char* vb = (const char*)&KV[vbuf][0];
        __builtin_amdgcn_s_setprio(1);
        #pragma unroll
        for (int ks = 0; ks < 4; ++ks) {
            const bf16x8 pf = *(const bf16x8*)(pbase + c * 272 + ((ks * 64 + g * 16) ^ swz));
            #pragma unroll
            for (int dt = 0; dt < 4; ++dt) {
                const int d = dt * 16 + c;
                const bf16x8 vf = *(const bf16x8*)(vb + d * 256 +
                        ((ks * 64 + g * 16) ^ ((d & 7) << 4)));
                oacc[dt] = __builtin_amdgcn_mfma_f32_16x16x32_bf16(pf, vf, oacc[dt], 0, 0, 0);
            }
        }
        __builtin_amdgcn_s_setprio(0);
        if (ch < 3) { __syncthreads(); vbuf ^= 1; }
    }

    // ---- softmax denom + output ----------------------------------------------
    se += __shfl_xor(se, 16); se += __shfl_xor(se, 32);
    const float inv = 1.f / se;          // for q-row c
    float iv[4];
    #pragma unroll
    for (int r = 0; r < 4; ++r) iv[r] = __shfl(inv, g * 4 + r);
    #pragma unroll
    for (int dt = 0; dt < 4; ++dt)
        #pragma unroll
        for (int r = 0; r < 4; ++r)
            A[((size_t)(b * 512 + q0 + g * 4 + r)) * 512 + h * 64 + dt * 16 + c] =
                f2b(oacc[dt][r] * iv[r]);
}

// ---------------- LayerNorm(X) — residual pre-summed into X by GEMM epilogue.
// Optional: f32 out Y, bf16 out Yb, carry accumulate Cacc/Cb, fused x9 = y.Ve.
__global__ __launch_bounds__(256)
void ln_res_kernel(const float* __restrict__ X,
                   const float* __restrict__ gp, const float* __restrict__ bp,
                   int lidx, float* __restrict__ Y, u16* __restrict__ Yb,
                   float* __restrict__ Cacc, u16* __restrict__ Cb,
                   const float* __restrict__ Ve, float* __restrict__ x9) {
    const int tid = threadIdx.x, w = tid >> 6, l = tid & 63;
    const size_t row = (size_t)blockIdx.x * 4 + w;
    const float g = gp[lidx], bb = bp[lidx];
    const float* x = X + row * 512;
    float v[8];
    const float4 a0 = *(const float4*)&x[l * 8], a1 = *(const float4*)&x[l * 8 + 4];
    v[0] = a0.x; v[1] = a0.y; v[2] = a0.z; v[3] = a0.w;
    v[4] = a1.x; v[5] = a1.y; v[6] = a1.z; v[7] = a1.w;
    float s = 0.f, sq = 0.f;
    #pragma unroll
    for (int i = 0; i < 8; ++i) { s += v[i]; sq = fmaf(v[i], v[i], sq); }
    #pragma unroll
    for (int o = 1; o < 64; o <<= 1) { s += __shfl_xor(s, o); sq += __shfl_xor(sq, o); }
    const float mu   = s * (1.f / 512.f);
    const float var  = (sq - 512.f * mu * mu) * (1.f / 511.f);
    const float rstd = rsqrtf(var + 1e-8f);
    float y[8];
    #pragma unroll
    for (int i = 0; i < 8; ++i) y[i] = fmaf((v[i] - mu) * rstd, g, bb);
    if (Y) {
        *(float4*)&Y[row * 512 + l * 8]     = *(float4*)&y[0];
        *(float4*)&Y[row * 512 + l * 8 + 4] = *(float4*)&y[4];
    }
    if (Yb) {
        u16x8 yb;
        #pragma unroll
        for (int i = 0; i < 8; ++i) yb[i] = f2b(y[i]);
        *(u16x8*)&Yb[row * 512 + l * 8] = yb;
    }
    if (Cacc) {
        float cv[8];
        float4 c0 = *(float4*)&Cacc[row * 512 + l * 8];
        float4 c1 = *(float4*)&Cacc[row * 512 + l * 8 + 4];
        cv[0] = c0.x + y[0]; cv[1] = c0.y + y[1]; cv[2] = c0.z + y[2]; cv[3] = c0.w + y[3];
        cv[4] = c1.x + y[4]; cv[5] = c1.y + y[5]; cv[6] = c1.z + y[6]; cv[7] = c1.w + y[7];
        *(float4*)&Cacc[row * 512 + l * 8]     = *(float4*)&cv[0];
        *(float4*)&Cacc[row * 512 + l * 8 + 4] = *(float4*)&cv[4];
        u16x8 cb;
        #pragma unroll
        for (int i = 0; i < 8; ++i) cb[i] = f2b(cv[i]);
        *(u16x8*)&Cb[row * 512 + l * 8] = cb;
    }
    if (Ve) {   // fused fin_ve: x9[row] = dot(y, Ve) (same per-lane+shuffle order)
        float dp = 0.f;
        #pragma unroll
        for (int i = 0; i < 8; ++i) dp = fmaf(y[i], Ve[l * 8 + i], dp);
        #pragma unroll
        for (int o = 1; o < 64; o <<= 1) dp += __shfl_xor(dp, o);
        if (l == 0) x9[row] = dp;
    }
}

// ---------------- fin_vd split-K: zp[sc][b][c] = sum_{s in chunk} x9*Vd -------
__global__ __launch_bounds__(256)
void fin_vd_part(const float* __restrict__ x9, const float* __restrict__ Vd,
                 float* __restrict__ zp) {
    __shared__ float xs[16][64];
    const int tid = threadIdx.x;
    const int c = blockIdx.x * 256 + tid;
    const int sc = blockIdx.y, s0 = sc * 64;
    #pragma unroll
    for (int p = 0; p < 4; ++p) {
        const int idx = p * 256 + tid;           // over [16][64]
        xs[idx >> 6][idx & 63] = x9[(idx >> 6) * 512 + s0 + (idx & 63)];
    }
    __syncthreads();
    float acc[16];
    #pragma unroll
    for (int b = 0; b < 16; ++b) acc[b] = 0.f;
    if (c < NCLS) {
        for (int s = 0; s < 64; ++s) {
            const float vd = Vd[(size_t)(s0 + s) * NCLS + c];
            #pragma unroll
            for (int b = 0; b < 16; ++b) acc[b] = fmaf(xs[b][s], vd, acc[b]);
        }
    }
    #pragma unroll
    for (int b = 0; b < 16; ++b)
        zp[((size_t)sc * 16 + b) * 10240 + c] = acc[b];
}

// ---------------- final norm (ddof=1 over 10000) + softmax -------------------
__global__ __launch_bounds__(256)
void fin_sm_kernel(const float* __restrict__ zp, const float* __restrict__ gp,
                   const float* __restrict__ bp, float* __restrict__ out) {
    __shared__ float zs[NCLS];
    __shared__ float red[4];
    __shared__ float red2[4];
    const int b = blockIdx.x, tid = threadIdx.x, w = tid >> 6, l = tid & 63;
    float s = 0.f, sq = 0.f;
    for (int i = tid; i < NCLS; i += 256) {
        float v = 0.f;
        #pragma unroll
        for (int sc = 0; sc < VD_SC; ++sc)
            v += zp[((size_t)sc * 16 + b) * 10240 + i];
        zs[i] = v; s += v; sq = fmaf(v, v, sq);
    }
    #pragma unroll
    for (int o = 1; o < 64; o <<= 1) { s += __shfl_xor(s, o); sq += __shfl_xor(sq, o); }
    if (l == 0) { red[w] = s; red2[w] = sq; }
    __syncthreads();
    s  = red[0] + red[1] + red[2] + red[3];
    sq = red2[0] + red2[1] + red2[2] + red2[3];
    const float mu   = s / 10000.f;
    const float var  = (sq - 10000.f * mu * mu) / 9999.f;
    const float rstd = rsqrtf(var + 1e-8f);
    const float g = gp[0], be = bp[0];
    __syncthreads();
    float mx = -1e30f;
    for (int i = tid; i < NCLS; i += 256) {
        const float e = fmaf((zs[i] - mu) * rstd, g, be);
        zs[i] = e; mx = fmaxf(mx, e);
    }
    #pragma unroll
    for (int o = 1; o < 64; o <<= 1) mx = fmaxf(mx, __shfl_xor(mx, o));
    if (l == 0) red[w] = mx;
    __syncthreads();
    mx = fmaxf(fmaxf(red[0], red[1]), fmaxf(red[2], red[3]));
    float es = 0.f;
    for (int i = tid; i < NCLS; i += 256) {
        const float p = expf(zs[i] - mx);
        zs[i] = p; es += p;
    }
    #pragma unroll
    for (int o = 1; o < 64; o <<= 1) es += __shfl_xor(es, o);
    if (l == 0) red2[w] = es;
    __syncthreads();
    es = red2[0] + red2[1] + red2[2] + red2[3];
    const float inv = 1.f / es;
    for (int i = tid; i < NCLS; i += 256) out[(size_t)b * NCLS + i] = zs[i] * inv;
}

// =============================================================================
extern "C" void kernel_launch(void* const* d_in, const int* in_sizes, int n_in,
                              void* d_out, int out_size, void* d_ws, size_t ws_size,
                              hipStream_t stream) {
    (void)in_sizes; (void)n_in; (void)out_size; (void)ws_size;
    const int*   xi  = (const int*)d_in[0];
    const float* emb = (const float*)d_in[1];
    const float* WQ  = (const float*)d_in[2];
    const float* WK  = (const float*)d_in[3];
    const float* WV  = (const float*)d_in[4];
    const float* WO  = (const float*)d_in[5];
    const float* W1  = (const float*)d_in[6];
    const float* b1  = (const float*)d_in[7];
    const float* W2  = (const float*)d_in[8];
    const float* b2  = (const float*)d_in[9];
    const float* ga  = (const float*)d_in[10];
    const float* ba  = (const float*)d_in[11];
    const float* g1  = (const float*)d_in[12];
    const float* be1 = (const float*)d_in[13];
    const float* g2  = (const float*)d_in[14];
    const float* be2 = (const float*)d_in[15];
    const float* Ve  = (const float*)d_in[16];
    const float* Vd  = (const float*)d_in[17];
    const float* gf  = (const float*)d_in[18];
    const float* bf  = (const float*)d_in[19];
    float* out = (float*)d_out;

    // ---------------- workspace layout ----------------
    float* ws  = (float*)d_ws;
    float* pos = ws;                        // 262144 f
    float* C   = pos + 262144;              // 4M f
    float* X2  = C   + 4194304;
    float* OUT = X2  + 4194304;             // (unused; kept for layout stability)
    float* PF  = OUT + 4194304;
    u16* ub = (u16*)(PF + 4194304);
    u16* Cb  = ub;  ub += 4194304;          // bf16 carry [8192][512]
    u16* X2b = ub;  ub += 4194304;          // bf16 x2    [8192][512]
    u16* Qbf = ub;  ub += 4194304;          // [8192][512] head-major cols; K at +4M, Vt at +8M
    u16* Kbf = ub;  ub += 4194304;
    u16* Vtb = ub;  ub += 4194304;          // [H*16][64][512]
    u16* Abf = ub;  ub += 4194304;          // attn out bf16 [8192][512]
    u16* Hb  = Qbf;                         // FF hidden [8192][2048] aliases Q|K|Vt|A
    float* zp = (float*)Vtb;                // fin_vd partials [8][16][10240] (Vtb dead)
    u16* WQKVb = ub; ub += 4718592;         // 6 x [1536][512]
    u16* WOt = ub; ub += 1572864;           // 6 x [512][512] (transposed)
    u16* W1t = ub; ub += 6291456;           // 6 x [2048][512] (transposed)
    u16* W2t = ub; ub += 6291456;           // 6 x [512][2048] (transposed)
    float* x9 = (float*)ub;                 // 8192 f

    pos_kernel<<<16, 512, 0, stream>>>(pos);
    embed_kernel<<<4096, 256, 0, stream>>>(xi, emb, pos, C, Cb);

    cvt3_kernel<<<4608, 256, 0, stream>>>(WQ, WK, WV, WQKVb);
    tcvt_b16_kernel<<<dim3(8,  8, 6), 256, 0, stream>>>(WO, WOt, 512, 512);
    tcvt_b16_kernel<<<dim3(8, 32, 6), 256, 0, stream>>>(W1, W1t, 512, 2048);
    tcvt_b16_kernel<<<dim3(32, 8, 6), 256, 0, stream>>>(W2, W2t, 2048, 512);

    const float scale = 1.0f / sqrtf(512.0f);

    for (int l = 0; l < NLAYER; ++l) {
        const u16* wqkv = WQKVb + (size_t)l * 786432;
        const u16* wo = WOt + (size_t)l * 262144;
        const u16* w1 = W1t + (size_t)l * 1048576;
        const u16* w2 = W2t + (size_t)l * 1048576;
        const bool last = (l == NLAYER - 1);

        gemm_bf16<128, EG_QKV3>     <<<dim3(64, 12), 512, 0, stream>>>(Cb, wqkv, nullptr, nullptr, Qbf, 1536, 512);
        attn_mfma                   <<<1024, 256, 0, stream>>>(Qbf, Kbf, Vtb, ga + l*8, ba + l*8, Abf, scale);
        // WO GEMM fuses the +C residual: PF = A@WO + C
        gemm_bf16<64, EG_F32>       <<<dim3(128, 4), 512, 0, stream>>>(Abf, wo, nullptr, C, PF, 512, 512);
        ln_res_kernel               <<<2048, 256, 0, stream>>>(PF, g1, be1, l, X2, X2b,
                                                               nullptr, nullptr, nullptr, nullptr);
        gemm_bf16<128, EG_BRELU_B16><<<dim3(64, 16), 512, 0, stream>>>(X2b, w1, b1 + l*2048, nullptr, Hb, 2048, 512);
        // FF2 GEMM fuses bias + X2 residual: PF = H@W2 + b2 + X2
        gemm_bf16<64, EG_BIAS_F32>  <<<dim3(128, 4), 512, 0, stream>>>(Hb, w2, b2 + l*512, X2, PF, 512, 2048);
        if (!last) {
            ln_res_kernel           <<<2048, 256, 0, stream>>>(PF, g2, be2, l, nullptr, nullptr,
                                                               C, Cb, nullptr, nullptr);
        } else {
            // last layer: only x9 = LN(PF).Ve is needed downstream
            ln_res_kernel           <<<2048, 256, 0, stream>>>(PF, g2, be2, l, nullptr, nullptr,
                                                               nullptr, nullptr, Ve, x9);
        }
    }

    fin_vd_part<<<dim3(40, VD_SC), 256, 0, stream>>>(x9, Vd, zp);
    fin_sm_kernel<<<16, 256, 0, stream>>>(zp, gf, bf, out);
}